// Round 6
// baseline (77.272 us; speedup 1.0000x reference)
//
#include <hip/hip_runtime.h>
#include <hip/hip_bf16.h>

#define UNITS  100000
#define N_IN   100000
#define DEGREE 16
#define NB     16   // batch
#define NF     4    // features
#define E_TOT  (UNITS * DEGREE)   // 1,600,000

#define G           4             // batch groups (4 b each), pinned to XCD pairs
#define BPG         (NB / G)      // 4
#define TU          128           // units per tile
#define TILES_PER_G ((UNITS + TU - 1) / TU)   // 782
#define NBLK        (G * TILES_PER_G)         // 3128

typedef float          f32x4 __attribute__((ext_vector_type(4)));
typedef unsigned short u16x8 __attribute__((ext_vector_type(8)));

__device__ __forceinline__ float bf2f(unsigned short u) {
    return __uint_as_float((unsigned)u << 16);
}

// ws layout (bytes)
#define XH_OFF   0u                       // ushort[G][N_IN][BPG][NF] = 12.8 MB
#define KH_OFF   12800000u                // ushort[E_TOT]            = 3.2 MB
#define BS_OFF   16000000u                // float[UNITS]             = 0.4 MB
#define CNT_OFF  16400000u                // int[G]
#define WS_NEED  (16400000u + 16u)

// ---------------------------------------------------------------------------
// Prep: (a) x[b][s][f] f32 -> xh[g][s][4b][4f] bf16 (32 B rows), (b) kern ->
// bf16, (c) bias -> per-unit sums, (d) zero ticket counters.
// ---------------------------------------------------------------------------
__global__ __launch_bounds__(256) void prep(
    const float4* __restrict__ x,     // [NB][N_IN]
    const float*  __restrict__ kern,  // [E]
    const float*  __restrict__ bias,  // [E]
    ushort4*       __restrict__ xh,   // [G*N_IN][BPG] (ushort4 = 4 bf16)
    unsigned short* __restrict__ kh,  // [E]
    float*         __restrict__ bsum, // [UNITS]
    int*           __restrict__ cnt)  // [G]
{
    __shared__ ushort4 tile[256][17];
    const int bid = (int)blockIdx.x;
    const int tid = (int)threadIdx.x;
    if (bid == 0 && tid < G) cnt[tid] = 0;

    if (bid < 391) {
        // --- transpose+convert x ---
        const int s0 = bid * 256;
#pragma unroll
        for (int b = 0; b < NB; ++b) {
            int s = s0 + tid;
            if (s < N_IN) {
                float4 v = x[(size_t)b * N_IN + s];
                ushort4 h;
                h.x = __bfloat16_as_ushort(__float2bfloat16(v.x));
                h.y = __bfloat16_as_ushort(__float2bfloat16(v.y));
                h.z = __bfloat16_as_ushort(__float2bfloat16(v.z));
                h.w = __bfloat16_as_ushort(__float2bfloat16(v.w));
                tile[tid][b] = h;
            }
        }
        __syncthreads();
#pragma unroll
        for (int j = 0; j < 16; ++j) {
            int idx = j * 256 + tid;      // (s_local, b)
            int sl  = idx >> 4;
            int b   = idx & 15;
            int s   = s0 + sl;
            if (s < N_IN) {
                int g = b >> 2, bl = b & 3;
                xh[((size_t)g * N_IN + s) * BPG + bl] = tile[sl][b];
            }
        }
    } else if (bid < 391 + 782) {
        // --- kern -> bf16, 8 per thread ---
        int base = (bid - 391) * 2048 + tid * 8;
        if (base < E_TOT) {
            float4 a = *(const float4*)(kern + base);
            float4 b4 = *(const float4*)(kern + base + 4);
            u16x8 h;
            h[0] = __bfloat16_as_ushort(__float2bfloat16(a.x));
            h[1] = __bfloat16_as_ushort(__float2bfloat16(a.y));
            h[2] = __bfloat16_as_ushort(__float2bfloat16(a.z));
            h[3] = __bfloat16_as_ushort(__float2bfloat16(a.w));
            h[4] = __bfloat16_as_ushort(__float2bfloat16(b4.x));
            h[5] = __bfloat16_as_ushort(__float2bfloat16(b4.y));
            h[6] = __bfloat16_as_ushort(__float2bfloat16(b4.z));
            h[7] = __bfloat16_as_ushort(__float2bfloat16(b4.w));
            *(u16x8*)(kh + base) = h;
        }
    } else {
        // --- bias -> per-unit sum (64 B contiguous per thread) ---
        int u = (bid - 1173) * 256 + tid;
        if (u < UNITS) {
            const float4* bp = (const float4*)(bias + (size_t)u * DEGREE);
            float4 b0 = bp[0], b1 = bp[1], b2 = bp[2], b3 = bp[3];
            float s01 = ((b0.x + b0.y) + (b0.z + b0.w)) +
                        ((b1.x + b1.y) + (b1.z + b1.w));
            float s23 = ((b2.x + b2.y) + (b2.z + b2.w)) +
                        ((b3.x + b3.y) + (b3.z + b3.w));
            bsum[u] = s01 + s23;
        }
    }
}

// ---------------------------------------------------------------------------
// Main: tile = 128 units x 4 batch (group g). Block reads its XCC_ID, claims
// a tile of its pinned g via atomic ticket (steals if exhausted -> correct
// under ANY dispatch mapping). Per-XCD gather set = 3.2 MB -> L2-resident.
// 2 lanes/edge x 16 B each cover the 32 B row (1 cache line).
// ---------------------------------------------------------------------------
__global__ __launch_bounds__(256) void pc_g4(
    const unsigned short* __restrict__ xh,   // [G][N_IN][16] bf16
    const unsigned short* __restrict__ kh,   // [E] bf16
    const float*          __restrict__ bsum, // [UNITS]
    const int*            __restrict__ src,  // [E]
    float*                __restrict__ out,  // [NB][UNITS][NF]
    int*                  __restrict__ cnt)  // [G]
{
    __shared__ int   s_sh[TU * 17];
    __shared__ float k_sh[TU * 17];
    __shared__ float bs_sh[TU];
    __shared__ int   claim2[2];

    const int tid = (int)threadIdx.x;
    if (tid == 0) {
        unsigned xcc = 0;
        asm volatile("s_getreg_b32 %0, hwreg(HW_REG_XCC_ID)" : "=s"(xcc));
        int g = (int)((xcc & 7u) >> 1);          // XCD pair -> group
        int t = atomicAdd(&cnt[g], 1);
#pragma unroll
        for (int k = 0; k < G - 1; ++k) {        // steal if my group is done
            if (t >= TILES_PER_G) { g = (g + 1) & (G - 1); t = atomicAdd(&cnt[g], 1); }
        }
        claim2[0] = g; claim2[1] = t;
    }
    __syncthreads();
    const int g    = claim2[0];
    const int tile = claim2[1];
    const int u0   = tile * TU;
    const int e0   = u0 * DEGREE;

    // Stage 2048 edges: src + bf16 kernel (read-once streams, nt-hinted).
#pragma unroll
    for (int it = 0; it < 8; ++it) {
        int idx = it * 256 + tid;                // 0..2047
        int ul  = idx >> 4;
        int sl  = ul * 17 + (idx & 15);
        if (u0 + ul < UNITS) {
            s_sh[sl] = __builtin_nontemporal_load(src + e0 + idx);
            unsigned short kv = __builtin_nontemporal_load(kh + e0 + idx);
            k_sh[sl] = bf2f(kv);
        } else { s_sh[sl] = 0; k_sh[sl] = 0.0f; }
    }
    if (tid < TU) {
        int u = u0 + tid;
        bs_sh[tid] = (u < UNITS) ? bsum[u] : 0.0f;
    }
    __syncthreads();

    const int ul = tid >> 1;          // unit-local 0..127
    const int p  = tid & 1;           // covers b = g*4 + 2p + {0,1}
    const unsigned short* xg = xh + (size_t)g * N_IN * 16;

    f32x4 a0 = {0.f, 0.f, 0.f, 0.f};
    f32x4 a1 = {0.f, 0.f, 0.f, 0.f};
#pragma unroll
    for (int d = 0; d < DEGREE; ++d) {
        int   s = s_sh[ul * 17 + d];             // conflict-free broadcast
        float k = k_sh[ul * 17 + d];
        u16x8 v = *(const u16x8*)(xg + (size_t)s * 16 + p * 8);  // 16 B
        a0.x = fmaf(k, bf2f(v[0]), a0.x);
        a0.y = fmaf(k, bf2f(v[1]), a0.y);
        a0.z = fmaf(k, bf2f(v[2]), a0.z);
        a0.w = fmaf(k, bf2f(v[3]), a0.w);
        a1.x = fmaf(k, bf2f(v[4]), a1.x);
        a1.y = fmaf(k, bf2f(v[5]), a1.y);
        a1.z = fmaf(k, bf2f(v[6]), a1.z);
        a1.w = fmaf(k, bf2f(v[7]), a1.w);
    }
    const float bs = bs_sh[ul];
    a0 += bs;
    a1 += bs;

    const int u = u0 + ul;
    if (u < UNITS) {
        int b0 = g * BPG + 2 * p;
        f32x4* o0 = (f32x4*)(out + ((size_t)b0 * UNITS + u) * NF);
        f32x4* o1 = (f32x4*)(out + ((size_t)(b0 + 1) * UNITS + u) * NF);
        __builtin_nontemporal_store(a0, o0);
        __builtin_nontemporal_store(a1, o1);
    }
}

// ---------------------------------------------------------------------------
// Mid-fallback (round-5 path, needs 12.8 MB ws)
// ---------------------------------------------------------------------------
__global__ __launch_bounds__(256) void conv_transpose(
    const float4* __restrict__ x, ushort4* __restrict__ xh)
{
    __shared__ ushort4 tile[256][17];
    const int tid = (int)threadIdx.x;
    const int s0  = (int)blockIdx.x * 256;
#pragma unroll
    for (int b = 0; b < NB; ++b) {
        int s = s0 + tid;
        if (s < N_IN) {
            float4 v = x[(size_t)b * N_IN + s];
            ushort4 h;
            h.x = __bfloat16_as_ushort(__float2bfloat16(v.x));
            h.y = __bfloat16_as_ushort(__float2bfloat16(v.y));
            h.z = __bfloat16_as_ushort(__float2bfloat16(v.z));
            h.w = __bfloat16_as_ushort(__float2bfloat16(v.w));
            tile[tid][b] = h;
        }
    }
    __syncthreads();
#pragma unroll
    for (int i = 0; i < 16; ++i) {
        int idx = i * 256 + tid;
        int sl  = idx >> 4;
        int b   = idx & 15;
        int s   = s0 + sl;
        if (s < N_IN) xh[(size_t)s * NB + b] = tile[sl][b];
    }
}

__global__ __launch_bounds__(256) void pc_main_h2(
    const unsigned short* __restrict__ xh, const float* __restrict__ kern,
    const float* __restrict__ bias, const int* __restrict__ src,
    float* __restrict__ out)
{
    __shared__ int   s_sh[32 * 17];
    __shared__ float k_sh[32 * 17];
    __shared__ float bsum_sh[32];
    __shared__ f32x4 o_sh[16][33];
    const int tid = (int)threadIdx.x;
    const int u0  = (int)blockIdx.x * 32;
    const int e0  = u0 * DEGREE;
#pragma unroll
    for (int h = 0; h < 2; ++h) {
        int idx = h * 256 + tid;
        int e   = e0 + idx;
        int ul  = idx >> 4;
        int d   = idx & 15;
        s_sh[ul * 17 + d] = __builtin_nontemporal_load(src + e);
        k_sh[ul * 17 + d] = __builtin_nontemporal_load(kern + e);
        float bv = __builtin_nontemporal_load(bias + e);
        for (int off = 8; off; off >>= 1) bv += __shfl_down(bv, off, 16);
        if (d == 0) bsum_sh[ul] = bv;
    }
    __syncthreads();
    const int ul = tid >> 3;
    const int p  = tid & 7;
    f32x4 a0 = {0.f,0.f,0.f,0.f}, a1 = {0.f,0.f,0.f,0.f};
#pragma unroll
    for (int d = 0; d < DEGREE; ++d) {
        int   s = s_sh[ul * 17 + d];
        float k = k_sh[ul * 17 + d];
        u16x8 v = *(const u16x8*)(xh + (size_t)s * 64 + p * 8);
        a0.x = fmaf(k, bf2f(v[0]), a0.x); a0.y = fmaf(k, bf2f(v[1]), a0.y);
        a0.z = fmaf(k, bf2f(v[2]), a0.z); a0.w = fmaf(k, bf2f(v[3]), a0.w);
        a1.x = fmaf(k, bf2f(v[4]), a1.x); a1.y = fmaf(k, bf2f(v[5]), a1.y);
        a1.z = fmaf(k, bf2f(v[6]), a1.z); a1.w = fmaf(k, bf2f(v[7]), a1.w);
    }
    const float bs = bsum_sh[ul];
    a0 += bs; a1 += bs;
    o_sh[2*p+0][ul] = a0;
    o_sh[2*p+1][ul] = a1;
    __syncthreads();
#pragma unroll
    for (int j = 0; j < 2; ++j) {
        int idx = j * 256 + tid;
        int b   = idx >> 5;
        int u   = idx & 31;
        f32x4 val = o_sh[b][u];
        f32x4* optr = (f32x4*)(out + ((size_t)b * UNITS + (u0 + u)) * NF);
        __builtin_nontemporal_store(val, optr);
    }
}

// ---------------------------------------------------------------------------
// Last-resort fallback (no workspace)
// ---------------------------------------------------------------------------
__global__ __launch_bounds__(256) void pc_fallback(
    const float* __restrict__ x, const float* __restrict__ kern,
    const float* __restrict__ bias, const int* __restrict__ src,
    float* __restrict__ out)
{
    const int UBLK = (UNITS + 255) / 256;
    int bid  = (int)blockIdx.x;
    int b_lo = bid & 7;
    int grp  = bid >> 3;
    int b    = b_lo + ((grp >= UBLK) ? 8 : 0);
    int ublk = (grp >= UBLK) ? (grp - UBLK) : grp;
    int u    = ublk * 256 + (int)threadIdx.x;
    if (u >= UNITS) return;
    const int e0 = u * DEGREE;
    int sidx[DEGREE]; float kv[DEGREE]; float bsumv = 0.0f;
#pragma unroll
    for (int q = 0; q < 4; ++q) {
        int4   s  = *(const int4*)  (src  + e0 + q * 4);
        float4 k  = *(const float4*)(kern + e0 + q * 4);
        float4 bb = *(const float4*)(bias + e0 + q * 4);
        sidx[q*4+0]=s.x; kv[q*4+0]=k.x; sidx[q*4+1]=s.y; kv[q*4+1]=k.y;
        sidx[q*4+2]=s.z; kv[q*4+2]=k.z; sidx[q*4+3]=s.w; kv[q*4+3]=k.w;
        bsumv += bb.x + bb.y + bb.z + bb.w;
    }
    const float* xb = x + (size_t)b * N_IN * NF;
    float4 acc = make_float4(bsumv, bsumv, bsumv, bsumv);
#pragma unroll
    for (int d = 0; d < DEGREE; ++d) {
        float4 xv = *(const float4*)(xb + (size_t)sidx[d] * NF);
        acc.x += kv[d]*xv.x; acc.y += kv[d]*xv.y;
        acc.z += kv[d]*xv.z; acc.w += kv[d]*xv.w;
    }
    *(float4*)(out + ((size_t)b * UNITS + u) * NF) = acc;
}

extern "C" void kernel_launch(void* const* d_in, const int* in_sizes, int n_in,
                              void* d_out, int out_size, void* d_ws, size_t ws_size,
                              hipStream_t stream) {
    const float* x    = (const float*)d_in[0];
    const float* kern = (const float*)d_in[1];
    const float* bias = (const float*)d_in[2];
    const int*   src  = (const int*)d_in[3];
    float* out = (float*)d_out;
    char* ws = (char*)d_ws;

    if (ws_size >= WS_NEED) {
        ushort4*        xh   = (ushort4*)(ws + XH_OFF);
        unsigned short* kh   = (unsigned short*)(ws + KH_OFF);
        float*          bsum = (float*)(ws + BS_OFF);
        int*            cnt  = (int*)(ws + CNT_OFF);
        prep<<<1564, 256, 0, stream>>>((const float4*)x, kern, bias,
                                       xh, kh, bsum, cnt);
        pc_g4<<<NBLK, 256, 0, stream>>>((const unsigned short*)xh, kh, bsum,
                                        src, out, cnt);
    } else if (ws_size >= (size_t)N_IN * NB * NF * sizeof(unsigned short)) {
        ushort4* xh = (ushort4*)d_ws;
        conv_transpose<<<(N_IN + 255) / 256, 256, 0, stream>>>(
            (const float4*)x, xh);
        pc_main_h2<<<UNITS / 32, 256, 0, stream>>>(
            (const unsigned short*)xh, kern, bias, src, out);
    } else {
        const int UBLK = (UNITS + 255) / 256;
        pc_fallback<<<NB * UBLK, 256, 0, stream>>>(x, kern, bias, src, out);
    }
}

// Round 7
// 69.838 us; speedup vs baseline: 1.1065x; 1.1065x over previous
//
#include <hip/hip_runtime.h>
#include <hip/hip_bf16.h>

#define UNITS  100000
#define N_IN   100000
#define DEGREE 16
#define NB     16
#define NF     4
#define E_TOT  (UNITS * DEGREE)

#define G           2                   // batch groups (8 b each) -> 64 B rows
#define BPG         (NB / G)            // 8
#define TU          64                  // units per tile
#define TILES       ((UNITS + TU - 1) / TU)   // 1563
#define NBLK        (G * TILES)               // 3126

typedef float          f32x4 __attribute__((ext_vector_type(4)));
typedef unsigned short u16x8 __attribute__((ext_vector_type(8)));

__device__ __forceinline__ float bf2f(unsigned short u) {
    return __uint_as_float((unsigned)u << 16);
}

// ws layout (bytes)
#define XH_OFF   0u            // ushort[G][N_IN][BPG][NF] = 12.8 MB (split, not dup)
#define KH_OFF   12800000u     // ushort[E_TOT] = 3.2 MB
#define BS_OFF   16000000u     // float[UNITS]  = 0.4 MB
#define CNT_OFF  16400000u     // int[G]
#define WS_NEED  (16400000u + 16u)

// ---------------------------------------------------------------------------
// Prep: (a) x[b][s][f] f32 -> xh[g][s][8b][4f] bf16 (64 B rows, 64 B aligned),
// (b) kern -> bf16, (c) bias -> per-unit sums, (d) zero tickets.
// ---------------------------------------------------------------------------
__global__ __launch_bounds__(256) void prep(
    const float4* __restrict__ x,
    const float*  __restrict__ kern,
    const float*  __restrict__ bias,
    ushort4*        __restrict__ xh,    // [(g*N_IN+s)*BPG + bl]
    unsigned short* __restrict__ kh,
    float*          __restrict__ bsum,
    int*            __restrict__ cnt)
{
    __shared__ ushort4 tile[256][17];
    const int bid = (int)blockIdx.x;
    const int tid = (int)threadIdx.x;
    if (bid == 0 && tid < G) cnt[tid] = 0;

    if (bid < 391) {
        const int s0 = bid * 256;
#pragma unroll
        for (int b = 0; b < NB; ++b) {
            int s = s0 + tid;
            if (s < N_IN) {
                float4 v = x[(size_t)b * N_IN + s];
                ushort4 h;
                h.x = __bfloat16_as_ushort(__float2bfloat16(v.x));
                h.y = __bfloat16_as_ushort(__float2bfloat16(v.y));
                h.z = __bfloat16_as_ushort(__float2bfloat16(v.z));
                h.w = __bfloat16_as_ushort(__float2bfloat16(v.w));
                tile[tid][b] = h;
            }
        }
        __syncthreads();
#pragma unroll
        for (int j = 0; j < 16; ++j) {
            int idx = j * 256 + tid;          // (s_local, b), b fastest
            int sl  = idx >> 4;
            int b   = idx & 15;
            int s   = s0 + sl;
            if (s < N_IN) {
                int g = b >> 3, bl = b & 7;
                xh[((size_t)g * N_IN + s) * BPG + bl] = tile[sl][b];
            }
        }
    } else if (bid < 391 + 782) {
        int base = (bid - 391) * 2048 + tid * 8;
        if (base < E_TOT) {
            float4 a = *(const float4*)(kern + base);
            float4 c = *(const float4*)(kern + base + 4);
            u16x8 h;
            h[0] = __bfloat16_as_ushort(__float2bfloat16(a.x));
            h[1] = __bfloat16_as_ushort(__float2bfloat16(a.y));
            h[2] = __bfloat16_as_ushort(__float2bfloat16(a.z));
            h[3] = __bfloat16_as_ushort(__float2bfloat16(a.w));
            h[4] = __bfloat16_as_ushort(__float2bfloat16(c.x));
            h[5] = __bfloat16_as_ushort(__float2bfloat16(c.y));
            h[6] = __bfloat16_as_ushort(__float2bfloat16(c.z));
            h[7] = __bfloat16_as_ushort(__float2bfloat16(c.w));
            *(u16x8*)(kh + base) = h;
        }
    } else {
        int u = (bid - 1173) * 256 + tid;
        if (u < UNITS) {
            const float4* bp = (const float4*)(bias + (size_t)u * DEGREE);
            float4 b0 = bp[0], b1 = bp[1], b2 = bp[2], b3 = bp[3];
            float s01 = ((b0.x + b0.y) + (b0.z + b0.w)) +
                        ((b1.x + b1.y) + (b1.z + b1.w));
            float s23 = ((b2.x + b2.y) + (b2.z + b2.w)) +
                        ((b3.x + b3.y) + (b3.z + b3.w));
            bsum[u] = s01 + s23;
        }
    }
}

// ---------------------------------------------------------------------------
// Main: tile = 64 units x 8 batch (group g = XCD-half). 4 lanes/edge x 16 B
// cover the 64 B row exactly (1 line-touch per edge per group; total 3.2 M =
// structural minimum). Per-group x footprint 6.4 MB -> resident in the
// pinned XCD-half's aggregate L2. Work-stealing tickets keep correctness
// under any dispatch->XCD mapping.
// ---------------------------------------------------------------------------
__global__ __launch_bounds__(256) void pc_g2(
    const unsigned short* __restrict__ xh,
    const unsigned short* __restrict__ kh,
    const float*          __restrict__ bsum,
    const int*            __restrict__ src,
    float*                __restrict__ out,
    int*                  __restrict__ cnt)
{
    __shared__ int   s_sh[TU * 17];
    __shared__ float k_sh[TU * 17];
    __shared__ float bs_sh[TU];
    __shared__ int   claim2[2];

    const int tid = (int)threadIdx.x;
    if (tid == 0) {
        unsigned xcc = 0;
        asm volatile("s_getreg_b32 %0, hwreg(HW_REG_XCC_ID)" : "=s"(xcc));
        int g = (int)(xcc & 1u);                 // XCD half -> group
        int t = atomicAdd(&cnt[g], 1);
        if (t >= TILES) { g ^= 1; t = atomicAdd(&cnt[g], 1); }
        claim2[0] = g; claim2[1] = t;
    }
    __syncthreads();
    const int g    = claim2[0];
    const int tile = claim2[1];
    if (tile >= TILES) return;                   // both groups exhausted
    const int u0 = tile * TU;
    const int e0 = u0 * DEGREE;

    // Stage 1024 edges (src + bf16 kernel), nt-hinted read-once streams.
#pragma unroll
    for (int it = 0; it < 4; ++it) {
        int idx = it * 256 + tid;                // 0..1023
        int ul  = idx >> 4;
        int sl  = ul * 17 + (idx & 15);
        if (u0 + ul < UNITS) {
            s_sh[sl] = __builtin_nontemporal_load(src + e0 + idx);
            unsigned short kv = __builtin_nontemporal_load(kh + e0 + idx);
            k_sh[sl] = bf2f(kv);
        } else { s_sh[sl] = 0; k_sh[sl] = 0.0f; }
    }
    if (tid < TU) {
        int u = u0 + tid;
        bs_sh[tid] = (u < UNITS) ? bsum[u] : 0.0f;
    }
    __syncthreads();

    const int ul = tid >> 2;          // unit-local 0..63
    const int q  = tid & 3;           // lane part: covers b = g*8 + 2q + {0,1}
    const unsigned short* xg = xh + (size_t)g * N_IN * 32;

    f32x4 a0 = {0.f, 0.f, 0.f, 0.f};
    f32x4 a1 = {0.f, 0.f, 0.f, 0.f};
#pragma unroll
    for (int d = 0; d < DEGREE; ++d) {
        int   s = s_sh[ul * 17 + d];             // broadcast among 4 lanes
        float k = k_sh[ul * 17 + d];
        u16x8 v = *(const u16x8*)(xg + (size_t)s * 32 + q * 8);  // 16 B
        a0.x = fmaf(k, bf2f(v[0]), a0.x);
        a0.y = fmaf(k, bf2f(v[1]), a0.y);
        a0.z = fmaf(k, bf2f(v[2]), a0.z);
        a0.w = fmaf(k, bf2f(v[3]), a0.w);
        a1.x = fmaf(k, bf2f(v[4]), a1.x);
        a1.y = fmaf(k, bf2f(v[5]), a1.y);
        a1.z = fmaf(k, bf2f(v[6]), a1.z);
        a1.w = fmaf(k, bf2f(v[7]), a1.w);
    }
    const float bs = bs_sh[ul];
    a0 += bs;
    a1 += bs;

    const int u = u0 + ul;
    if (u < UNITS) {
        int b0 = g * BPG + 2 * q;
        f32x4* o0 = (f32x4*)(out + ((size_t)b0 * UNITS + u) * NF);
        f32x4* o1 = (f32x4*)(out + ((size_t)(b0 + 1) * UNITS + u) * NF);
        __builtin_nontemporal_store(a0, o0);
        __builtin_nontemporal_store(a1, o1);
    }
}

// ---------------------------------------------------------------------------
// Fallback (no/small workspace): round-1 kernel.
// ---------------------------------------------------------------------------
__global__ __launch_bounds__(256) void pc_fallback(
    const float* __restrict__ x, const float* __restrict__ kern,
    const float* __restrict__ bias, const int* __restrict__ src,
    float* __restrict__ out)
{
    const int UBLK = (UNITS + 255) / 256;
    int bid  = (int)blockIdx.x;
    int b_lo = bid & 7;
    int grp  = bid >> 3;
    int b    = b_lo + ((grp >= UBLK) ? 8 : 0);
    int ublk = (grp >= UBLK) ? (grp - UBLK) : grp;
    int u    = ublk * 256 + (int)threadIdx.x;
    if (u >= UNITS) return;
    const int e0 = u * DEGREE;
    int sidx[DEGREE]; float kv[DEGREE]; float bsumv = 0.0f;
#pragma unroll
    for (int qq = 0; qq < 4; ++qq) {
        int4   s  = *(const int4*)  (src  + e0 + qq * 4);
        float4 k  = *(const float4*)(kern + e0 + qq * 4);
        float4 bb = *(const float4*)(bias + e0 + qq * 4);
        sidx[qq*4+0]=s.x; kv[qq*4+0]=k.x; sidx[qq*4+1]=s.y; kv[qq*4+1]=k.y;
        sidx[qq*4+2]=s.z; kv[qq*4+2]=k.z; sidx[qq*4+3]=s.w; kv[qq*4+3]=k.w;
        bsumv += bb.x + bb.y + bb.z + bb.w;
    }
    const float* xb = x + (size_t)b * N_IN * NF;
    float4 acc = make_float4(bsumv, bsumv, bsumv, bsumv);
#pragma unroll
    for (int d = 0; d < DEGREE; ++d) {
        float4 xv = *(const float4*)(xb + (size_t)sidx[d] * NF);
        acc.x += kv[d]*xv.x; acc.y += kv[d]*xv.y;
        acc.z += kv[d]*xv.z; acc.w += kv[d]*xv.w;
    }
    *(float4*)(out + ((size_t)b * UNITS + u) * NF) = acc;
}

extern "C" void kernel_launch(void* const* d_in, const int* in_sizes, int n_in,
                              void* d_out, int out_size, void* d_ws, size_t ws_size,
                              hipStream_t stream) {
    const float* x    = (const float*)d_in[0];
    const float* kern = (const float*)d_in[1];
    const float* bias = (const float*)d_in[2];
    const int*   src  = (const int*)d_in[3];
    float* out = (float*)d_out;
    char* ws = (char*)d_ws;

    if (ws_size >= WS_NEED) {
        ushort4*        xh   = (ushort4*)(ws + XH_OFF);
        unsigned short* kh   = (unsigned short*)(ws + KH_OFF);
        float*          bsum = (float*)(ws + BS_OFF);
        int*            cnt  = (int*)(ws + CNT_OFF);
        prep<<<1564, 256, 0, stream>>>((const float4*)x, kern, bias,
                                       xh, kh, bsum, cnt);
        pc_g2<<<NBLK, 256, 0, stream>>>((const unsigned short*)xh, kh, bsum,
                                        src, out, cnt);
    } else {
        const int UBLK = (UNITS + 255) / 256;
        pc_fallback<<<NB * UBLK * 2, 256, 0, stream>>>(x, kern, bias, src, out);
    }
}

// Round 8
// 49.866 us; speedup vs baseline: 1.5496x; 1.4005x over previous
//
#include <hip/hip_runtime.h>
#include <hip/hip_bf16.h>

#define UNITS  100000
#define N_IN   100000
#define DEGREE 16
#define NB     16
#define NF     4
#define E_TOT  (UNITS * DEGREE)

#define G      2                          // batch groups (8 b each) -> 64 B rows
#define BPG    (NB / G)                   // 8
#define TU     64                         // units per tile
#define TILES  ((UNITS + TU - 1) / TU)    // 1563
#define NBLK   (G * TILES)                // 3126

typedef float          f32x4 __attribute__((ext_vector_type(4)));
typedef unsigned short u16x8 __attribute__((ext_vector_type(8)));

__device__ __forceinline__ float bf2f(unsigned short u) {
    return __uint_as_float((unsigned)u << 16);
}

// ws layout (bytes)
#define XH_OFF   0u            // ushort[G][N_IN][BPG][NF] = 12.8 MB (split)
#define BS_OFF   12800000u     // float[UNITS] = 0.4 MB
#define WS_NEED  13200000u

// ---------------------------------------------------------------------------
// Prep: (a) x[b][s][f] f32 -> xh[g][s][8b][4f] bf16 (64 B rows, 64 B aligned);
// (b) bias -> per-unit sums.
// ---------------------------------------------------------------------------
__global__ __launch_bounds__(256) void prep(
    const float4* __restrict__ x,
    const float*  __restrict__ bias,
    ushort4*      __restrict__ xh,     // [(g*N_IN+s)*BPG + bl]
    float*        __restrict__ bsum)
{
    __shared__ ushort4 tile[256][17];
    const int bid = (int)blockIdx.x;
    const int tid = (int)threadIdx.x;

    if (bid < 391) {
        const int s0 = bid * 256;
#pragma unroll
        for (int b = 0; b < NB; ++b) {
            int s = s0 + tid;
            if (s < N_IN) {
                float4 v = x[(size_t)b * N_IN + s];
                ushort4 h;
                h.x = __bfloat16_as_ushort(__float2bfloat16(v.x));
                h.y = __bfloat16_as_ushort(__float2bfloat16(v.y));
                h.z = __bfloat16_as_ushort(__float2bfloat16(v.z));
                h.w = __bfloat16_as_ushort(__float2bfloat16(v.w));
                tile[tid][b] = h;
            }
        }
        __syncthreads();
#pragma unroll
        for (int j = 0; j < 16; ++j) {
            int idx = j * 256 + tid;        // (s_local, b), b fastest
            int sl  = idx >> 4;
            int b   = idx & 15;
            int s   = s0 + sl;
            if (s < N_IN) {
                int g = b >> 3, bl = b & 7;
                xh[((size_t)g * N_IN + s) * BPG + bl] = tile[sl][b];
            }
        }
    } else {
        int u = (bid - 391) * 256 + tid;
        if (u < UNITS) {
            const float4* bp = (const float4*)(bias + (size_t)u * DEGREE);
            float4 b0 = bp[0], b1 = bp[1], b2 = bp[2], b3 = bp[3];
            float s01 = ((b0.x + b0.y) + (b0.z + b0.w)) +
                        ((b1.x + b1.y) + (b1.z + b1.w));
            float s23 = ((b2.x + b2.y) + (b2.z + b2.w)) +
                        ((b3.x + b3.y) + (b3.z + b3.w));
            bsum[u] = s01 + s23;
        }
    }
}

// ---------------------------------------------------------------------------
// Main: tile = 64 units x 8 batch. g = blockIdx&1 -> XCD parity pin under
// round-robin dispatch (locality only; correct under any mapping). 4 lanes x
// 16 B cover each 64 B row (1 line/edge/group; 3.2 M total = floor). All 16
// gathers issued before the FMA chain (deep MLP vs MSHR-latency bound).
// ---------------------------------------------------------------------------
__global__ __launch_bounds__(256, 4) void pc_g2b(
    const unsigned short* __restrict__ xh,
    const float*          __restrict__ kern,  // [E] f32
    const float*          __restrict__ bsum,  // [UNITS]
    const int*            __restrict__ src,   // [E]
    float*                __restrict__ out)   // [NB][UNITS][NF]
{
    __shared__ int   s_sh[TU * 17];
    __shared__ float k_sh[TU * 17];
    __shared__ float bs_sh[TU];

    const int tid  = (int)threadIdx.x;
    const int bid  = (int)blockIdx.x;
    const int g    = bid & 1;
    const int tile = bid >> 1;
    const int u0   = tile * TU;
    const int e0   = u0 * DEGREE;

    // Stage 1024 edges (src + f32 kernel), nt-hinted read-once streams.
#pragma unroll
    for (int it = 0; it < 4; ++it) {
        int idx = it * 256 + tid;             // 0..1023
        int ul  = idx >> 4;
        int sl  = ul * 17 + (idx & 15);
        if (u0 + ul < UNITS) {
            s_sh[sl] = __builtin_nontemporal_load(src + e0 + idx);
            k_sh[sl] = __builtin_nontemporal_load(kern + e0 + idx);
        } else { s_sh[sl] = 0; k_sh[sl] = 0.0f; }
    }
    if (tid < TU) {
        int u = u0 + tid;
        bs_sh[tid] = (u < UNITS) ? bsum[u] : 0.0f;
    }
    __syncthreads();

    const int ul = tid >> 2;                  // unit-local 0..63
    const int q  = tid & 3;                   // covers b = g*8 + 2q + {0,1}
    const unsigned short* xg = xh + (size_t)g * N_IN * 32;

    // Issue all 16 gathers first (16 lines in flight per thread), then FMA.
    u16x8 v[8], w[8];
#pragma unroll
    for (int d = 0; d < 8; ++d) {
        int s = s_sh[ul * 17 + d];
        v[d] = *(const u16x8*)(xg + (size_t)s * 32 + q * 8);
    }
#pragma unroll
    for (int d = 0; d < 8; ++d) {
        int s = s_sh[ul * 17 + 8 + d];
        w[d] = *(const u16x8*)(xg + (size_t)s * 32 + q * 8);
    }

    f32x4 a0 = {0.f, 0.f, 0.f, 0.f};
    f32x4 a1 = {0.f, 0.f, 0.f, 0.f};
#pragma unroll
    for (int d = 0; d < 8; ++d) {
        float k = k_sh[ul * 17 + d];
        a0.x = fmaf(k, bf2f(v[d][0]), a0.x);
        a0.y = fmaf(k, bf2f(v[d][1]), a0.y);
        a0.z = fmaf(k, bf2f(v[d][2]), a0.z);
        a0.w = fmaf(k, bf2f(v[d][3]), a0.w);
        a1.x = fmaf(k, bf2f(v[d][4]), a1.x);
        a1.y = fmaf(k, bf2f(v[d][5]), a1.y);
        a1.z = fmaf(k, bf2f(v[d][6]), a1.z);
        a1.w = fmaf(k, bf2f(v[d][7]), a1.w);
    }
#pragma unroll
    for (int d = 0; d < 8; ++d) {
        float k = k_sh[ul * 17 + 8 + d];
        a0.x = fmaf(k, bf2f(w[d][0]), a0.x);
        a0.y = fmaf(k, bf2f(w[d][1]), a0.y);
        a0.z = fmaf(k, bf2f(w[d][2]), a0.z);
        a0.w = fmaf(k, bf2f(w[d][3]), a0.w);
        a1.x = fmaf(k, bf2f(w[d][4]), a1.x);
        a1.y = fmaf(k, bf2f(w[d][5]), a1.y);
        a1.z = fmaf(k, bf2f(w[d][6]), a1.z);
        a1.w = fmaf(k, bf2f(w[d][7]), a1.w);
    }

    const float bs = bs_sh[ul];
    a0 += bs;
    a1 += bs;

    const int u = u0 + ul;
    if (u < UNITS) {
        int b0 = g * BPG + 2 * q;
        f32x4* o0 = (f32x4*)(out + ((size_t)b0 * UNITS + u) * NF);
        f32x4* o1 = (f32x4*)(out + ((size_t)(b0 + 1) * UNITS + u) * NF);
        __builtin_nontemporal_store(a0, o0);
        __builtin_nontemporal_store(a1, o1);
    }
}

// ---------------------------------------------------------------------------
// Fallback (no/small workspace): round-1 kernel.
// ---------------------------------------------------------------------------
__global__ __launch_bounds__(256) void pc_fallback(
    const float* __restrict__ x, const float* __restrict__ kern,
    const float* __restrict__ bias, const int* __restrict__ src,
    float* __restrict__ out)
{
    const int UBLK = (UNITS + 255) / 256;
    int bid  = (int)blockIdx.x;
    int b_lo = bid & 7;
    int grp  = bid >> 3;
    int b    = b_lo + ((grp >= UBLK) ? 8 : 0);
    int ublk = (grp >= UBLK) ? (grp - UBLK) : grp;
    int u    = ublk * 256 + (int)threadIdx.x;
    if (u >= UNITS) return;
    const int e0 = u * DEGREE;
    int sidx[DEGREE]; float kv[DEGREE]; float bsumv = 0.0f;
#pragma unroll
    for (int qq = 0; qq < 4; ++qq) {
        int4   s  = *(const int4*)  (src  + e0 + qq * 4);
        float4 k  = *(const float4*)(kern + e0 + qq * 4);
        float4 bb = *(const float4*)(bias + e0 + qq * 4);
        sidx[qq*4+0]=s.x; kv[qq*4+0]=k.x; sidx[qq*4+1]=s.y; kv[qq*4+1]=k.y;
        sidx[qq*4+2]=s.z; kv[qq*4+2]=k.z; sidx[qq*4+3]=s.w; kv[qq*4+3]=k.w;
        bsumv += bb.x + bb.y + bb.z + bb.w;
    }
    const float* xb = x + (size_t)b * N_IN * NF;
    float4 acc = make_float4(bsumv, bsumv, bsumv, bsumv);
#pragma unroll
    for (int d = 0; d < DEGREE; ++d) {
        float4 xv = *(const float4*)(xb + (size_t)sidx[d] * NF);
        acc.x += kv[d]*xv.x; acc.y += kv[d]*xv.y;
        acc.z += kv[d]*xv.z; acc.w += kv[d]*xv.w;
    }
    *(float4*)(out + ((size_t)b * UNITS + u) * NF) = acc;
}

extern "C" void kernel_launch(void* const* d_in, const int* in_sizes, int n_in,
                              void* d_out, int out_size, void* d_ws, size_t ws_size,
                              hipStream_t stream) {
    const float* x    = (const float*)d_in[0];
    const float* kern = (const float*)d_in[1];
    const float* bias = (const float*)d_in[2];
    const int*   src  = (const int*)d_in[3];
    float* out = (float*)d_out;
    char* ws = (char*)d_ws;

    if (ws_size >= WS_NEED) {
        ushort4* xh   = (ushort4*)(ws + XH_OFF);
        float*   bsum = (float*)(ws + BS_OFF);
        prep<<<391 + 391, 256, 0, stream>>>((const float4*)x, bias, xh, bsum);
        pc_g2b<<<NBLK, 256, 0, stream>>>((const unsigned short*)xh, kern,
                                         bsum, src, out);
    } else {
        const int UBLK = (UNITS + 255) / 256;
        pc_fallback<<<NB * UBLK * 2, 256, 0, stream>>>(x, kern, bias, src, out);
    }
}

// Round 9
// 42.563 us; speedup vs baseline: 1.8155x; 1.1716x over previous
//
#include <hip/hip_runtime.h>
#include <hip/hip_bf16.h>

#define UNITS  100000
#define N_IN   100000
#define DEGREE 16
#define NB     16
#define NF     4
#define E_TOT  (UNITS * DEGREE)

#define TU     32                         // units per main block
#define NBLK   (UNITS / TU)               // 3125

typedef float          f32x4 __attribute__((ext_vector_type(4)));
typedef unsigned short u16x8 __attribute__((ext_vector_type(8)));

__device__ __forceinline__ float bf2f(unsigned short u) {
    return __uint_as_float((unsigned)u << 16);
}

// ws layout (bytes)
#define XH_OFF   0u            // ushort[N_IN][NB][NF] = 12.8 MB (128 B rows)
#define BS_OFF   12800000u     // float[UNITS] = 0.4 MB
#define WS_NEED  13200000u

// ---------------------------------------------------------------------------
// Prep: (a) x[b][s][f] f32 -> xh[s][16b][4f] bf16 — one aligned 128 B line
// per s (the gather-touch floor: 1 line per edge); (b) bias -> per-unit sums.
// ---------------------------------------------------------------------------
__global__ __launch_bounds__(256) void prep(
    const float4* __restrict__ x,      // [NB][N_IN]
    const float*  __restrict__ bias,   // [E]
    ushort4*      __restrict__ xh,     // [N_IN*NB]
    float*        __restrict__ bsum)   // [UNITS]
{
    __shared__ ushort4 tile[256][17];
    const int bid = (int)blockIdx.x;
    const int tid = (int)threadIdx.x;

    if (bid < 391) {
        const int s0 = bid * 256;
#pragma unroll
        for (int b = 0; b < NB; ++b) {
            int s = s0 + tid;
            if (s < N_IN) {
                float4 v = x[(size_t)b * N_IN + s];
                ushort4 h;
                h.x = __bfloat16_as_ushort(__float2bfloat16(v.x));
                h.y = __bfloat16_as_ushort(__float2bfloat16(v.y));
                h.z = __bfloat16_as_ushort(__float2bfloat16(v.z));
                h.w = __bfloat16_as_ushort(__float2bfloat16(v.w));
                tile[tid][b] = h;
            }
        }
        __syncthreads();
#pragma unroll
        for (int j = 0; j < 16; ++j) {
            int idx = j * 256 + tid;        // (s_local, b), b fastest
            int sl  = idx >> 4;
            int b   = idx & 15;
            int s   = s0 + sl;
            if (s < N_IN) xh[(size_t)s * NB + b] = tile[sl][b];
        }
    } else {
        int u = (bid - 391) * 256 + tid;
        if (u < UNITS) {
            const float4* bp = (const float4*)(bias + (size_t)u * DEGREE);
            float4 b0 = bp[0], b1 = bp[1], b2 = bp[2], b3 = bp[3];
            float s01 = ((b0.x + b0.y) + (b0.z + b0.w)) +
                        ((b1.x + b1.y) + (b1.z + b1.w));
            float s23 = ((b2.x + b2.y) + (b2.z + b2.w)) +
                        ((b3.x + b3.y) + (b3.z + b3.w));
            bsum[u] = s01 + s23;
        }
    }
}

// ---------------------------------------------------------------------------
// Main (R5 structure, proven fastest): 32 units x 8 lanes/edge x 16 B.
// Each edge's gather = ONE aligned 128 B line (touch floor = E = 1.6 M).
// Edge stream (src + f32 kern) staged via LDS once, bsum precomputed,
// output transposed through LDS for coalesced nontemporal stores.
// ---------------------------------------------------------------------------
__global__ __launch_bounds__(256) void pc_h3(
    const unsigned short* __restrict__ xh,    // [N_IN][16] bf16, 128 B rows
    const float*          __restrict__ kern,  // [E]
    const float*          __restrict__ bsum,  // [UNITS]
    const int*            __restrict__ src,   // [E]
    float*                __restrict__ out)   // [NB][UNITS][NF]
{
    __shared__ int   s_sh[TU * 17];
    __shared__ float k_sh[TU * 17];
    __shared__ float bs_sh[TU];
    __shared__ f32x4 o_sh[16][33];

    const int tid = (int)threadIdx.x;
    const int u0  = (int)blockIdx.x * TU;
    const int e0  = u0 * DEGREE;

    // Stage 512 edges (read-once streams, nt-hinted).
#pragma unroll
    for (int h = 0; h < 2; ++h) {
        int idx = h * 256 + tid;              // 0..511
        int ul  = idx >> 4;
        int sl  = ul * 17 + (idx & 15);
        s_sh[sl] = __builtin_nontemporal_load(src + e0 + idx);
        k_sh[sl] = __builtin_nontemporal_load(kern + e0 + idx);
    }
    if (tid < TU) bs_sh[tid] = bsum[u0 + tid];
    __syncthreads();

    const int ul = tid >> 3;                  // unit-local 0..31
    const int p  = tid & 7;                   // covers b = 2p, 2p+1

    f32x4 a0 = {0.f, 0.f, 0.f, 0.f};
    f32x4 a1 = {0.f, 0.f, 0.f, 0.f};
#pragma unroll
    for (int d = 0; d < DEGREE; ++d) {
        int   s = s_sh[ul * 17 + d];          // conflict-free broadcast
        float k = k_sh[ul * 17 + d];
        u16x8 v = *(const u16x8*)(xh + (size_t)s * 64 + p * 8);  // 16 B
        a0.x = fmaf(k, bf2f(v[0]), a0.x);
        a0.y = fmaf(k, bf2f(v[1]), a0.y);
        a0.z = fmaf(k, bf2f(v[2]), a0.z);
        a0.w = fmaf(k, bf2f(v[3]), a0.w);
        a1.x = fmaf(k, bf2f(v[4]), a1.x);
        a1.y = fmaf(k, bf2f(v[5]), a1.y);
        a1.z = fmaf(k, bf2f(v[6]), a1.z);
        a1.w = fmaf(k, bf2f(v[7]), a1.w);
    }
    const float bs = bs_sh[ul];
    a0 += bs;
    a1 += bs;

    o_sh[2 * p + 0][ul] = a0;
    o_sh[2 * p + 1][ul] = a1;
    __syncthreads();

    // Coalesced output: consecutive tid -> consecutive u within a b-panel.
#pragma unroll
    for (int j = 0; j < 2; ++j) {
        int idx = j * 256 + tid;              // 0..511
        int b   = idx >> 5;                   // 0..15
        int u   = idx & 31;
        f32x4 val = o_sh[b][u];
        f32x4* optr = (f32x4*)(out + ((size_t)b * UNITS + (u0 + u)) * NF);
        __builtin_nontemporal_store(val, optr);
    }
}

// ---------------------------------------------------------------------------
// Fallback (no/small workspace): round-1 kernel.
// ---------------------------------------------------------------------------
__global__ __launch_bounds__(256) void pc_fallback(
    const float* __restrict__ x, const float* __restrict__ kern,
    const float* __restrict__ bias, const int* __restrict__ src,
    float* __restrict__ out)
{
    const int UBLK = (UNITS + 255) / 256;
    int bid  = (int)blockIdx.x;
    int b_lo = bid & 7;
    int grp  = bid >> 3;
    int b    = b_lo + ((grp >= UBLK) ? 8 : 0);
    int ublk = (grp >= UBLK) ? (grp - UBLK) : grp;
    int u    = ublk * 256 + (int)threadIdx.x;
    if (u >= UNITS) return;
    const int e0 = u * DEGREE;
    int sidx[DEGREE]; float kv[DEGREE]; float bsumv = 0.0f;
#pragma unroll
    for (int qq = 0; qq < 4; ++qq) {
        int4   s  = *(const int4*)  (src  + e0 + qq * 4);
        float4 k  = *(const float4*)(kern + e0 + qq * 4);
        float4 bb = *(const float4*)(bias + e0 + qq * 4);
        sidx[qq*4+0]=s.x; kv[qq*4+0]=k.x; sidx[qq*4+1]=s.y; kv[qq*4+1]=k.y;
        sidx[qq*4+2]=s.z; kv[qq*4+2]=k.z; sidx[qq*4+3]=s.w; kv[qq*4+3]=k.w;
        bsumv += bb.x + bb.y + bb.z + bb.w;
    }
    const float* xb = x + (size_t)b * N_IN * NF;
    float4 acc = make_float4(bsumv, bsumv, bsumv, bsumv);
#pragma unroll
    for (int d = 0; d < DEGREE; ++d) {
        float4 xv = *(const float4*)(xb + (size_t)sidx[d] * NF);
        acc.x += kv[d]*xv.x; acc.y += kv[d]*xv.y;
        acc.z += kv[d]*xv.z; acc.w += kv[d]*xv.w;
    }
    *(float4*)(out + ((size_t)b * UNITS + u) * NF) = acc;
}

extern "C" void kernel_launch(void* const* d_in, const int* in_sizes, int n_in,
                              void* d_out, int out_size, void* d_ws, size_t ws_size,
                              hipStream_t stream) {
    const float* x    = (const float*)d_in[0];
    const float* kern = (const float*)d_in[1];
    const float* bias = (const float*)d_in[2];
    const int*   src  = (const int*)d_in[3];
    float* out = (float*)d_out;
    char* ws = (char*)d_ws;

    if (ws_size >= WS_NEED) {
        ushort4* xh   = (ushort4*)(ws + XH_OFF);
        float*   bsum = (float*)(ws + BS_OFF);
        prep<<<391 + 391, 256, 0, stream>>>((const float4*)x, bias, xh, bsum);
        pc_h3<<<NBLK, 256, 0, stream>>>((const unsigned short*)xh, kern,
                                        bsum, src, out);
    } else {
        const int UBLK = (UNITS + 255) / 256;
        pc_fallback<<<NB * UBLK * 2, 256, 0, stream>>>(x, kern, bias, src, out);
    }
}

// Round 10
// 41.916 us; speedup vs baseline: 1.8435x; 1.0154x over previous
//
#include <hip/hip_runtime.h>
#include <hip/hip_bf16.h>

#define UNITS  100000
#define N_IN   100000
#define DEGREE 16
#define NB     16
#define NF     4
#define E_TOT  (UNITS * DEGREE)

#define TU     32                         // units per main block
#define NBLK   (UNITS / TU)               // 3125

typedef float          f32x4 __attribute__((ext_vector_type(4)));
typedef unsigned short u16x8 __attribute__((ext_vector_type(8)));

__device__ __forceinline__ float bf2f(unsigned short u) {
    return __uint_as_float((unsigned)u << 16);
}

// ws layout (bytes)
#define XH_OFF   0u            // ushort[N_IN][NB][NF] = 12.8 MB (128 B rows)
#define BS_OFF   12800000u     // float[UNITS] = 0.4 MB
#define WS_NEED  13200000u

// ---------------------------------------------------------------------------
// Prep: (a) x[b][s][f] f32 -> xh[s][16b][4f] bf16 (one aligned 128 B line per
// s = the gather-touch floor); (b) bias -> per-unit sums.
// ---------------------------------------------------------------------------
__global__ __launch_bounds__(256) void prep(
    const float4* __restrict__ x,      // [NB][N_IN]
    const float*  __restrict__ bias,   // [E]
    ushort4*      __restrict__ xh,     // [N_IN*NB]
    float*        __restrict__ bsum)   // [UNITS]
{
    __shared__ ushort4 tile[256][17];
    const int bid = (int)blockIdx.x;
    const int tid = (int)threadIdx.x;

    if (bid < 391) {
        const int s0 = bid * 256;
#pragma unroll
        for (int b = 0; b < NB; ++b) {
            int s = s0 + tid;
            if (s < N_IN) {
                float4 v = x[(size_t)b * N_IN + s];
                ushort4 h;
                h.x = __bfloat16_as_ushort(__float2bfloat16(v.x));
                h.y = __bfloat16_as_ushort(__float2bfloat16(v.y));
                h.z = __bfloat16_as_ushort(__float2bfloat16(v.z));
                h.w = __bfloat16_as_ushort(__float2bfloat16(v.w));
                tile[tid][b] = h;
            }
        }
        __syncthreads();
#pragma unroll
        for (int j = 0; j < 16; ++j) {
            int idx = j * 256 + tid;        // (s_local, b), b fastest
            int sl  = idx >> 4;
            int b   = idx & 15;
            int s   = s0 + sl;
            if (s < N_IN) xh[(size_t)s * NB + b] = tile[sl][b];
        }
    } else {
        int u = (bid - 391) * 256 + tid;
        if (u < UNITS) {
            const float4* bp = (const float4*)(bias + (size_t)u * DEGREE);
            float4 b0 = bp[0], b1 = bp[1], b2 = bp[2], b3 = bp[3];
            float s01 = ((b0.x + b0.y) + (b0.z + b0.w)) +
                        ((b1.x + b1.y) + (b1.z + b1.w));
            float s23 = ((b2.x + b2.y) + (b2.z + b2.w)) +
                        ((b3.x + b3.y) + (b3.z + b3.w));
            bsum[u] = s01 + s23;
        }
    }
}

// ---------------------------------------------------------------------------
// Main: R9 structure + DEEP GATHER BATCH — all 16 row-loads issued into
// registers before the FMA chain (16 outstanding 128 B lines per thread).
// Discriminates fill-BW-bound (null) vs miss-concurrency-bound (wins).
// ---------------------------------------------------------------------------
__global__ __launch_bounds__(256, 4) void pc_h4(
    const unsigned short* __restrict__ xh,    // [N_IN][16] bf16, 128 B rows
    const float*          __restrict__ kern,  // [E]
    const float*          __restrict__ bsum,  // [UNITS]
    const int*            __restrict__ src,   // [E]
    float*                __restrict__ out)   // [NB][UNITS][NF]
{
    __shared__ int   s_sh[TU * 17];
    __shared__ float k_sh[TU * 17];
    __shared__ float bs_sh[TU];
    __shared__ f32x4 o_sh[16][33];

    const int tid = (int)threadIdx.x;
    const int u0  = (int)blockIdx.x * TU;
    const int e0  = u0 * DEGREE;

    // Stage 512 edges (read-once streams, nt-hinted).
#pragma unroll
    for (int h = 0; h < 2; ++h) {
        int idx = h * 256 + tid;              // 0..511
        int ul  = idx >> 4;
        int sl  = ul * 17 + (idx & 15);
        s_sh[sl] = __builtin_nontemporal_load(src + e0 + idx);
        k_sh[sl] = __builtin_nontemporal_load(kern + e0 + idx);
    }
    if (tid < TU) bs_sh[tid] = bsum[u0 + tid];
    __syncthreads();

    const int ul = tid >> 3;                  // unit-local 0..31
    const int p  = tid & 7;                   // covers b = 2p, 2p+1

    // Issue all 16 gathers first: 16 x 128 B lines in flight per thread.
    u16x8 v[DEGREE];
#pragma unroll
    for (int d = 0; d < DEGREE; ++d) {
        int s = s_sh[ul * 17 + d];            // conflict-free broadcast
        v[d] = *(const u16x8*)(xh + (size_t)s * 64 + p * 8);  // 16 B
    }

    f32x4 a0 = {0.f, 0.f, 0.f, 0.f};
    f32x4 a1 = {0.f, 0.f, 0.f, 0.f};
#pragma unroll
    for (int d = 0; d < DEGREE; ++d) {
        float k = k_sh[ul * 17 + d];
        a0.x = fmaf(k, bf2f(v[d][0]), a0.x);
        a0.y = fmaf(k, bf2f(v[d][1]), a0.y);
        a0.z = fmaf(k, bf2f(v[d][2]), a0.z);
        a0.w = fmaf(k, bf2f(v[d][3]), a0.w);
        a1.x = fmaf(k, bf2f(v[d][4]), a1.x);
        a1.y = fmaf(k, bf2f(v[d][5]), a1.y);
        a1.z = fmaf(k, bf2f(v[d][6]), a1.z);
        a1.w = fmaf(k, bf2f(v[d][7]), a1.w);
    }
    const float bs = bs_sh[ul];
    a0 += bs;
    a1 += bs;

    o_sh[2 * p + 0][ul] = a0;
    o_sh[2 * p + 1][ul] = a1;
    __syncthreads();

    // Coalesced output: consecutive tid -> consecutive u within a b-panel.
#pragma unroll
    for (int j = 0; j < 2; ++j) {
        int idx = j * 256 + tid;              // 0..511
        int b   = idx >> 5;                   // 0..15
        int u   = idx & 31;
        f32x4 val = o_sh[b][u];
        f32x4* optr = (f32x4*)(out + ((size_t)b * UNITS + (u0 + u)) * NF);
        __builtin_nontemporal_store(val, optr);
    }
}

// ---------------------------------------------------------------------------
// Fallback (no/small workspace): round-1 kernel.
// ---------------------------------------------------------------------------
__global__ __launch_bounds__(256) void pc_fallback(
    const float* __restrict__ x, const float* __restrict__ kern,
    const float* __restrict__ bias, const int* __restrict__ src,
    float* __restrict__ out)
{
    const int UBLK = (UNITS + 255) / 256;
    int bid  = (int)blockIdx.x;
    int b_lo = bid & 7;
    int grp  = bid >> 3;
    int b    = b_lo + ((grp >= UBLK) ? 8 : 0);
    int ublk = (grp >= UBLK) ? (grp - UBLK) : grp;
    int u    = ublk * 256 + (int)threadIdx.x;
    if (u >= UNITS) return;
    const int e0 = u * DEGREE;
    int sidx[DEGREE]; float kv[DEGREE]; float bsumv = 0.0f;
#pragma unroll
    for (int qq = 0; qq < 4; ++qq) {
        int4   s  = *(const int4*)  (src  + e0 + qq * 4);
        float4 k  = *(const float4*)(kern + e0 + qq * 4);
        float4 bb = *(const float4*)(bias + e0 + qq * 4);
        sidx[qq*4+0]=s.x; kv[qq*4+0]=k.x; sidx[qq*4+1]=s.y; kv[qq*4+1]=k.y;
        sidx[qq*4+2]=s.z; kv[qq*4+2]=k.z; sidx[qq*4+3]=s.w; kv[qq*4+3]=k.w;
        bsumv += bb.x + bb.y + bb.z + bb.w;
    }
    const float* xb = x + (size_t)b * N_IN * NF;
    float4 acc = make_float4(bsumv, bsumv, bsumv, bsumv);
#pragma unroll
    for (int d = 0; d < DEGREE; ++d) {
        float4 xv = *(const float4*)(xb + (size_t)sidx[d] * NF);
        acc.x += kv[d]*xv.x; acc.y += kv[d]*xv.y;
        acc.z += kv[d]*xv.z; acc.w += kv[d]*xv.w;
    }
    *(float4*)(out + ((size_t)b * UNITS + u) * NF) = acc;
}

extern "C" void kernel_launch(void* const* d_in, const int* in_sizes, int n_in,
                              void* d_out, int out_size, void* d_ws, size_t ws_size,
                              hipStream_t stream) {
    const float* x    = (const float*)d_in[0];
    const float* kern = (const float*)d_in[1];
    const float* bias = (const float*)d_in[2];
    const int*   src  = (const int*)d_in[3];
    float* out = (float*)d_out;
    char* ws = (char*)d_ws;

    if (ws_size >= WS_NEED) {
        ushort4* xh   = (ushort4*)(ws + XH_OFF);
        float*   bsum = (float*)(ws + BS_OFF);
        prep<<<391 + 391, 256, 0, stream>>>((const float4*)x, bias, xh, bsum);
        pc_h4<<<NBLK, 256, 0, stream>>>((const unsigned short*)xh, kern,
                                        bsum, src, out);
    } else {
        const int UBLK = (UNITS + 255) / 256;
        pc_fallback<<<NB * UBLK * 2, 256, 0, stream>>>(x, kern, bias, src, out);
    }
}